// Round 5
// baseline (455.452 us; speedup 1.0000x reference)
//
#include <hip/hip_runtime.h>

#define Nn 4096
#define Cc 256
#define NN2 ((size_t)Nn * Nn)

typedef __attribute__((ext_vector_type(8))) short bf16x8;
typedef __attribute__((ext_vector_type(4))) short bf16x4;
typedef __attribute__((ext_vector_type(4))) float f32x4;

// async global->LDS DMA, 16B per lane, wave-uniform LDS base + lane*16
#define GLOAD(src, dst) __builtin_amdgcn_global_load_lds( \
    (const __attribute__((address_space(1))) void*)(src), \
    (__attribute__((address_space(3))) void*)(dst), 16, 0, 0)

__device__ __forceinline__ unsigned short f2bf(float f) {
    union { float f; unsigned u; } v; v.f = f;
    unsigned r = v.u + 0x7FFF + ((v.u >> 16) & 1);
    return (unsigned short)(r >> 16);
}

__device__ __forceinline__ bf16x8 pack2(const float4& a, const float4& b) {
    bf16x8 o;
    o[0] = (short)f2bf(a.x); o[1] = (short)f2bf(a.y);
    o[2] = (short)f2bf(a.z); o[3] = (short)f2bf(a.w);
    o[4] = (short)f2bf(b.x); o[5] = (short)f2bf(b.y);
    o[6] = (short)f2bf(b.z); o[7] = (short)f2bf(b.w);
    return o;
}

// exp 4 floats, accumulate into sacc, pack bf16x4, 8B LDS store
__device__ __forceinline__ void expstore4(const float4& a,
                                          unsigned short* dst, float& sacc) {
    const float s0 = __expf(a.x), s1 = __expf(a.y), s2 = __expf(a.z), s3 = __expf(a.w);
    sacc += (s0 + s1) + (s2 + s3);
    bf16x4 o;
    o[0] = (short)f2bf(s0); o[1] = (short)f2bf(s1);
    o[2] = (short)f2bf(s2); o[3] = (short)f2bf(s3);
    *(bf16x4*)dst = o;
}

// ---------------------------------------------------------------------------
// Kernel 1: V[b,o,n] = bf16( sum_c W[o,c]*X[b,c,n] + bias[o] )  (unchanged)
// ---------------------------------------------------------------------------
__global__ __launch_bounds__(256) void value_gemm(
    const float* __restrict__ X, const float* __restrict__ W,
    const float* __restrict__ bias, unsigned short* __restrict__ Vout)
{
    __shared__ float Xs[256][33];

    const int t = threadIdx.x;
    const int b  = blockIdx.x >> 7;
    const int n0 = (blockIdx.x & 127) << 5;
    const int wave = t >> 6, lane = t & 63;
    const int lrow = lane & 15, lq = lane >> 4;

    const float* Xb = X + (size_t)b * Cc * Nn + n0;

    {
        const int r0 = t >> 3, c4 = (t & 7) << 2;
        #pragma unroll
        for (int i = 0; i < 8; ++i) {
            const int r = r0 + i * 32;
            const float4 v = *(const float4*)(Xb + (size_t)r * Nn + c4);
            Xs[r][c4 + 0] = v.x; Xs[r][c4 + 1] = v.y;
            Xs[r][c4 + 2] = v.z; Xs[r][c4 + 3] = v.w;
        }
    }
    __syncthreads();

    f32x4 acc[4][2] = {};

    #pragma unroll 2
    for (int k0 = 0; k0 < Cc; k0 += 32) {
        bf16x8 af[4];
        #pragma unroll
        for (int ci = 0; ci < 4; ++ci) {
            const float* wp = W + (size_t)(wave * 64 + ci * 16 + lrow) * Cc + k0 + lq * 8;
            af[ci] = pack2(*(const float4*)wp, *(const float4*)(wp + 4));
        }
        bf16x8 bp[2];
        #pragma unroll
        for (int mi = 0; mi < 2; ++mi) {
            const int n = mi * 16 + lrow;
            bf16x8 o;
            #pragma unroll
            for (int j = 0; j < 8; ++j) o[j] = (short)f2bf(Xs[k0 + lq * 8 + j][n]);
            bp[mi] = o;
        }
        #pragma unroll
        for (int ci = 0; ci < 4; ++ci)
            #pragma unroll
            for (int mi = 0; mi < 2; ++mi)
                acc[ci][mi] = __builtin_amdgcn_mfma_f32_16x16x32_bf16(
                    af[ci], bp[mi], acc[ci][mi], 0, 0, 0);
    }

    #pragma unroll
    for (int ci = 0; ci < 4; ++ci) {
        #pragma unroll
        for (int rr = 0; rr < 4; ++rr) {
            const int o = wave * 64 + ci * 16 + lq * 4 + rr;
            const float bo = bias[o];
            #pragma unroll
            for (int mi = 0; mi < 2; ++mi) {
                const int n = n0 + mi * 16 + lrow;
                Vout[((size_t)(b * Cc + o)) * Nn + n] = f2bf(acc[ci][mi][rr] + bo);
            }
        }
    }
}

// ---------------------------------------------------------------------------
// Kernel 2 v5: DMA-staged E with counted vmcnt (T3+T4) so the compiler
// CANNOT collapse the prefetch (global_load_lds is side-effecting, 0 VGPR).
// 3-stage pipeline, ONE barrier/step:
//   DMA Eraw(t+3) -> 4-slot LDS ring   (2 tiles always in flight, vmcnt(6))
//   exp-pass: Eraw(t+1) -> exp -> Bexp[(t+1)&1]  (bf16, swizzled)
//   MFMA: consume Bexp[t&1] x V(t) register ping-pong (loaded at t-1)
// Wave w owns exclusive c-slice [w*32,w*32+32) x m=32 rows. Grid 512 =
// 2 blocks/CU; b=(blk&7)>>1 pins batch to an XCD pair for V L2 residency.
// ---------------------------------------------------------------------------
__global__ __launch_bounds__(512, 4) void attn_gemm(
    const unsigned short* __restrict__ V, const float* __restrict__ E,
    const float* __restrict__ X, const float* __restrict__ gamma,
    float* __restrict__ Out)
{
    __shared__ float Eraw[4][32 * 64];           // raw E tiles, DMA ring (32 KB)
    __shared__ unsigned short Bexp[2][32 * 64];  // exp(E) [m][k] bf16, swizzled (8 KB)
    __shared__ float sum_lds[32];

    const int t = threadIdx.x;
    const int wave = t >> 6, lane = t & 63;
    const int lrow = lane & 15, lq = lane >> 4;
    const int l7 = lrow & 7;
    const int blk = blockIdx.x;
    const int b  = (blk & 7) >> 1;                       // batch -> XCD pair
    const int m0 = (((blk >> 3) << 1) | (blk & 1)) << 5; // 32-row m-tile

    // exp-pass ownership: thread owns (erow, 4 floats at col eg*4)
    const int erow = t >> 4, eg = t & 15;
    const int eslot = erow * 64 + eg * 4;                // f32 idx in Eraw slot
    // Bexp slot (round-2/4-verified swizzle)
    const int ss = erow * 64 + (((eg >> 1) ^ (erow & 7)) << 3) + ((eg & 1) << 2);

    // DMA addressing: wave stages rows wave*4..+3 (1 KB); lane -> row wave*4+(lane>>4),
    // col (lane&15)*4. LDS dest = &Eraw[slot][wave*256] + lane*16B (linear, matches).
    const int drow = wave * 4 + (lane >> 4);
    const float* egbase = E + (size_t)b * NN2 + (size_t)(m0 + drow) * Nn + ((lane & 15) << 2);

    // V fragments: rows wave*32 + ci*16 + lrow, cols lq*8 (+ k*64 + kk*32)
    const unsigned short* vbase = V + (size_t)(b * Cc + wave * 32) * Nn;
    const int voff0 = lrow * Nn + lq * 8;
    const int voff1 = (16 + lrow) * Nn + lq * 8;

    f32x4 acc[2][2] = {};   // [ci][mi]
    float sacc = 0.f;
    bf16x8 vA[4], vB[4];    // [kk*2+ci] ping-pong

    // ---- prologue: DMA tiles 0,1,2; V(0); exp tile 0 -> Bexp[0] ----
    GLOAD(egbase,            &Eraw[0][wave * 256]);
    GLOAD(egbase + (1 << 6), &Eraw[1][wave * 256]);
    GLOAD(egbase + (2 << 6), &Eraw[2][wave * 256]);
    vA[0] = *(const bf16x8*)(vbase + voff0);
    vA[1] = *(const bf16x8*)(vbase + voff1);
    vA[2] = *(const bf16x8*)(vbase + voff0 + 32);
    vA[3] = *(const bf16x8*)(vbase + voff1 + 32);
    asm volatile("s_waitcnt vmcnt(6)" ::: "memory");     // DMA(0) retired
    __builtin_amdgcn_s_barrier();
    {
        const float4 ev = *(const float4*)&Eraw[0][eslot];
        expstore4(ev, &Bexp[0][ss], sacc);
    }

    // One step of the pipeline. Vc = consume regs, Vn = next-load regs.
    // Per-step order: LDSBAR | V(T+1) loads | DMA(T+3) | bfr ds_reads |
    // vmcnt(#VMC) | exp-pass(T+1) | MFMA(T).
#define STEP(T, Vc, Vn, DO_DMA, DO_EXP, DO_VL, VMC)                            \
    {                                                                          \
        asm volatile("s_waitcnt lgkmcnt(0)" ::: "memory");                     \
        __builtin_amdgcn_s_barrier();                                          \
        if (DO_VL) {                                                           \
            const int kv = ((T) + 1) << 6;                                     \
            Vn[0] = *(const bf16x8*)(vbase + voff0 + kv);                      \
            Vn[1] = *(const bf16x8*)(vbase + voff1 + kv);                      \
            Vn[2] = *(const bf16x8*)(vbase + voff0 + kv + 32);                 \
            Vn[3] = *(const bf16x8*)(vbase + voff1 + kv + 32);                 \
        }                                                                      \
        if (DO_DMA) {                                                          \
            GLOAD(egbase + (((T) + 3) << 6), &Eraw[((T) + 3) & 3][wave * 256]);\
        }                                                                      \
        bf16x8 bfr[2][2];                                                      \
        _Pragma("unroll")                                                      \
        for (int kk = 0; kk < 2; ++kk)                                         \
            _Pragma("unroll")                                                  \
            for (int mi = 0; mi < 2; ++mi) {                                   \
                const int rm = mi * 16 + lrow;                                 \
                bfr[kk][mi] = *(const bf16x8*)                                 \
                    &Bexp[(T) & 1][rm * 64 + (((kk * 4 + lq) ^ l7) << 3)];     \
            }                                                                  \
        asm volatile("s_waitcnt vmcnt(" #VMC ")" ::: "memory");                \
        if (DO_EXP) {                                                          \
            const float4 ev = *(const float4*)&Eraw[((T) + 1) & 3][eslot];     \
            expstore4(ev, &Bexp[((T) + 1) & 1][ss], sacc);                     \
        }                                                                      \
        __builtin_amdgcn_s_setprio(1);                                         \
        _Pragma("unroll")                                                      \
        for (int ci = 0; ci < 2; ++ci)                                         \
            _Pragma("unroll")                                                  \
            for (int mi = 0; mi < 2; ++mi) {                                   \
                acc[ci][mi] = __builtin_amdgcn_mfma_f32_16x16x32_bf16(         \
                    Vc[0 * 2 + ci], bfr[0][mi], acc[ci][mi], 0, 0, 0);         \
                acc[ci][mi] = __builtin_amdgcn_mfma_f32_16x16x32_bf16(         \
                    Vc[1 * 2 + ci], bfr[1][mi], acc[ci][mi], 0, 0, 0);         \
            }                                                                  \
        __builtin_amdgcn_s_setprio(0);                                         \
    }

    // ---- main loop: steps 0..60 steady (vmcnt 6), tail 61..63 ----
    #pragma unroll 1
    for (int k = 0; k < 60; k += 2) {
        STEP(k,     vA, vB, 1, 1, 1, 6);
        STEP(k + 1, vB, vA, 1, 1, 1, 6);
    }
    STEP(60, vA, vB, 1, 1, 1, 6);
    STEP(61, vB, vA, 0, 1, 1, 0);
    STEP(62, vA, vB, 0, 1, 1, 0);
    STEP(63, vB, vA, 0, 0, 0, 0);
#undef STEP

    // ---- softmax denominators: 16 owner-threads per m-row, same wave ----
    {
        float s = sacc;
        s += __shfl_xor(s, 1);
        s += __shfl_xor(s, 2);
        s += __shfl_xor(s, 4);
        s += __shfl_xor(s, 8);
        if (eg == 0) sum_lds[erow] = s;
    }
    __syncthreads();

    // ---- epilogue ----
    const float g = gamma[0];
    #pragma unroll
    for (int mi = 0; mi < 2; ++mi) {
        const int mloc = mi * 16 + lrow;
        const float scale = g / sum_lds[mloc];
        const int m = m0 + mloc;
        #pragma unroll
        for (int ci = 0; ci < 2; ++ci) {
            #pragma unroll
            for (int rr = 0; rr < 4; ++rr) {
                const int c = wave * 32 + ci * 16 + lq * 4 + rr;
                const size_t off = ((size_t)(b * Cc + c)) * Nn + m;
                Out[off] = scale * acc[ci][mi][rr] + 2.0f * X[off];
            }
        }
    }
}

extern "C" void kernel_launch(void* const* d_in, const int* in_sizes, int n_in,
                              void* d_out, int out_size, void* d_ws, size_t ws_size,
                              hipStream_t stream) {
    const float* energy  = (const float*)d_in[0];  // [4,4096,4096]
    const float* x       = (const float*)d_in[1];  // [4,256,64,64]
    const float* value_w = (const float*)d_in[2];  // [256,256]
    const float* value_b = (const float*)d_in[3];  // [256]
    const float* gamma   = (const float*)d_in[4];  // [1]
    float* out = (float*)d_out;
    unsigned short* Vws = (unsigned short*)d_ws;   // 4*256*4096 bf16 = 8 MB

    value_gemm<<<512, 256, 0, stream>>>(x, value_w, value_b, Vws);
    attn_gemm<<<512, 512, 0, stream>>>(Vws, energy, x, gamma, out);
}